// Round 3
// baseline (305.490 us; speedup 1.0000x reference)
//
#include <hip/hip_runtime.h>
#include <hip/hip_bf16.h>

typedef __hip_bfloat16 bf16;
typedef __attribute__((ext_vector_type(8))) short short8;
typedef __attribute__((ext_vector_type(4))) float f32x4;

__device__ __forceinline__ float b2f(bf16 v) { return __bfloat162float(v); }
__device__ __forceinline__ bf16 f2b(float v) { return __float2bfloat16(v); }
__device__ __forceinline__ short f2bs(float v) {
    bf16 b = f2b(v);
    return *reinterpret_cast<short*>(&b);
}
__device__ __forceinline__ float bflo(unsigned int u) { return __uint_as_float(u << 16); }
__device__ __forceinline__ float bfhi(unsigned int u) { return __uint_as_float(u & 0xffff0000u); }
__device__ __forceinline__ unsigned int packbf(float lo, float hi) {
    bf16 l = f2b(lo), h = f2b(hi);
    return ((unsigned int)(*(unsigned short*)&h) << 16) | (*(unsigned short*)&l);
}

// DTYPE (resolved rounds 0-9): inputs fp32, output fp32; intermediates bf16.
// Perm note (r20): buckets emitted DESCENDING by degree (LPT dispatch order) so
// heavy blocks launch first and short blocks backfill the tail.
// r2 (this session): GAT edge loop restructured 32->8 lanes/edge (8 ch/lane).
// Issue count/edge ~13 -> ~8 (1 shfl instead of 3, shared across 4 edges;
// uint4 gathers). Edge->accumulator partition kept bit-identical to the old
// l0..l3 unroll (group g = edges beg+g, beg+g+4, ...; xor8/xor16 combine tree
// == old pairwise tree).

__global__ void k_sentinel(float* out, int n, float val) {
    int i = blockIdx.x * blockDim.x + threadIdx.x;
    if (i < n) out[i] = val;
}

// ---------------- setup: weight repacks + TyB (blocks 0..168) || edge count (rest) ----------------
#define PREP_BLOCKS 169
__global__ void k_setup(const float* __restrict__ Wl, const float* __restrict__ Wr,
                        const float* __restrict__ Wres, const float* __restrict__ Wp,
                        const float* __restrict__ W1, const float* __restrict__ Et,
                        const float* __restrict__ bp,
                        bf16* __restrict__ WT, bf16* __restrict__ WpT,
                        bf16* __restrict__ W1T, float* __restrict__ TyB,
                        const int* __restrict__ edst, int* __restrict__ counts,
                        int* __restrict__ rank, int e) {
    int b = blockIdx.x;
    if (b < PREP_BLOCKS) {
        int i = b * 256 + threadIdx.x;
        if (i < 36864) {
            int l = i / 12288, rem = i % 12288;
            int col = rem / 64, k = rem % 64;
            int mat = col >> 6, c = col & 63;
            const float* W = (mat == 0) ? Wl : (mat == 1) ? Wr : Wres;
            WT[i] = f2b(W[l * 4096 + k * 64 + c]);
        } else if (i < 40960) {
            int j = i - 36864, col = j / 64, k = j % 64;
            WpT[j] = f2b(Wp[k * 64 + col]);
        } else if (i < 43008) {
            int j = i - 40960, col = j / 64, k = j % 64;
            W1T[j] = f2b(W1[k * 32 + col]);
        } else if (i < 43200) {
            int j = i - 43008, t = j / 64, d = j % 64;
            float s = bp[d];
#pragma unroll
            for (int f = 0; f < 16; ++f) s += Et[t * 16 + f] * Wp[(64 + f) * 64 + d];
            TyB[j] = s;
        }
    } else {
        int i = (b - PREP_BLOCKS) * 256 + threadIdx.x;
        if (i < e) rank[i] = atomicAdd(&counts[edst[i]], 1);
    }
}

// ---------------- encoder + layer-0 xform fused ----------------
__global__ __launch_bounds__(256) void k_encx(
        const float* __restrict__ x, const int* __restrict__ ntype,
        const float* __restrict__ Wt, const float* __restrict__ bt,
        const bf16* __restrict__ WpT, const float* __restrict__ TyB,
        bf16* __restrict__ h0b,
        const bf16* __restrict__ WT0, const float* __restrict__ bl0,
        const float* __restrict__ br0, const float* __restrict__ bc0,
        bf16* __restrict__ xlo, bf16* __restrict__ xro, bf16* __restrict__ reso,
        int n) {
    __shared__ float sWt[512];
    __shared__ float sbt[64];
    __shared__ __align__(16) short sh[4 * 16 * 72];
    int tid = threadIdx.x;
    for (int i = tid; i < 512; i += 256) sWt[i] = Wt[i];
    if (tid < 64) sbt[tid] = bt[tid];
    __syncthreads();
    int wave = tid >> 6, lane = tid & 63;
    int nb = blockIdx.x * 64 + wave * 16;
    if (nb >= n) return;
    int m = lane & 15, q = lane >> 4;
    short* shw = sh + wave * 16 * 72;

    const float* xrow = x + (size_t)(nb + m) * 8;
    float xv[8];
#pragma unroll
    for (int f = 0; f < 8; ++f) xv[f] = xrow[f];

    short8 a0, a1;
#pragma unroll
    for (int j = 0; j < 8; ++j) {
        int c0 = q * 8 + j, c1 = 32 + q * 8 + j;
        float s0 = sbt[c0], s1 = sbt[c1];
#pragma unroll
        for (int f = 0; f < 8; ++f) {
            s0 += xv[f] * sWt[f * 64 + c0];
            s1 += xv[f] * sWt[f * 64 + c1];
        }
        a0[j] = f2bs(fmaxf(s0, 0.f));
        a1[j] = f2bs(fmaxf(s1, 0.f));
    }

    int ty[4];
#pragma unroll
    for (int r = 0; r < 4; ++r) ty[r] = ntype[nb + q * 4 + r];

#pragma unroll
    for (int t = 0; t < 4; ++t) {
        const short* wp = (const short*)(WpT + (size_t)(t * 16 + m) * 64) + q * 8;
        short8 b0 = *(const short8*)(wp);
        short8 b1 = *(const short8*)(wp + 32);
        f32x4 acc = {0.f, 0.f, 0.f, 0.f};
        acc = __builtin_amdgcn_mfma_f32_16x16x32_bf16(a0, b0, acc, 0, 0, 0);
        acc = __builtin_amdgcn_mfma_f32_16x16x32_bf16(a1, b1, acc, 0, 0, 0);
        int col = t * 16 + m;
#pragma unroll
        for (int r = 0; r < 4; ++r) {
            int nd = nb + q * 4 + r;
            short vb = f2bs(acc[r] + TyB[ty[r] * 64 + col]);
            h0b[(size_t)nd * 64 + col] = *reinterpret_cast<bf16*>(&vb);
            shw[(q * 4 + r) * 72 + col] = vb;
        }
    }
    short8 ha0 = *(const short8*)(&shw[m * 72 + q * 8]);
    short8 ha1 = *(const short8*)(&shw[m * 72 + 32 + q * 8]);
#pragma unroll
    for (int t = 0; t < 12; ++t) {
        const short* wp = (const short*)(WT0 + (size_t)(t * 16 + m) * 64) + q * 8;
        short8 b0 = *(const short8*)(wp);
        short8 b1 = *(const short8*)(wp + 32);
        f32x4 acc = {0.f, 0.f, 0.f, 0.f};
        acc = __builtin_amdgcn_mfma_f32_16x16x32_bf16(ha0, b0, acc, 0, 0, 0);
        acc = __builtin_amdgcn_mfma_f32_16x16x32_bf16(ha1, b1, acc, 0, 0, 0);
        int col = t * 16 + m;
        int mat = col >> 6, c = col & 63;
        float bias = (mat == 0) ? bl0[c] : (mat == 1) ? br0[c] : bc0[c];
        bf16* dst = (mat == 0) ? xlo : (mat == 1) ? xro : reso;
#pragma unroll
        for (int r = 0; r < 4; ++r)
            dst[(size_t)(nb + q * 4 + r) * 64 + c] = f2b(acc[r] + bias);
    }
}

// ---------------- CSR scan + degree histogram (bucket = 63 - min(deg,63): LPT) ----------------
__global__ void k_scan_local(const int* __restrict__ counts, int* __restrict__ row_raw,
                             int* __restrict__ bsum, int* __restrict__ hist, int n) {
    __shared__ int part[256];
    __shared__ int lh[64];
    int tid = threadIdx.x;
    if (tid < 64) lh[tid] = 0;
    __syncthreads();
    int base = blockIdx.x * 1024 + tid * 4;
    int d0 = (base     < n) ? counts[base]     : -1;
    int d1 = (base + 1 < n) ? counts[base + 1] : -1;
    int d2 = (base + 2 < n) ? counts[base + 2] : -1;
    int d3 = (base + 3 < n) ? counts[base + 3] : -1;
    if (d0 >= 0) atomicAdd(&lh[63 - (d0 < 63 ? d0 : 63)], 1);
    if (d1 >= 0) atomicAdd(&lh[63 - (d1 < 63 ? d1 : 63)], 1);
    if (d2 >= 0) atomicAdd(&lh[63 - (d2 < 63 ? d2 : 63)], 1);
    if (d3 >= 0) atomicAdd(&lh[63 - (d3 < 63 ? d3 : 63)], 1);
    int c0 = d0 + 1, c1 = d1 + 1, c2 = d2 + 1, c3 = d3 + 1;
    part[tid] = c0 + c1 + c2 + c3;
    __syncthreads();
    for (int off = 1; off < 256; off <<= 1) {
        int t = (tid >= off) ? part[tid - off] : 0;
        __syncthreads();
        part[tid] += t;
        __syncthreads();
    }
    int ex = (tid == 0) ? 0 : part[tid - 1];
    if (base     < n) row_raw[base]     = ex;
    if (base + 1 < n) row_raw[base + 1] = ex + c0;
    if (base + 2 < n) row_raw[base + 2] = ex + c0 + c1;
    if (base + 3 < n) row_raw[base + 3] = ex + c0 + c1 + c2;
    if (tid == 255) bsum[blockIdx.x] = part[255];
    if (tid < 64 && lh[tid] > 0) atomicAdd(&hist[tid], lh[tid]);
}

__global__ void k_scan_bsum(int* __restrict__ bsum, int* __restrict__ row_ptr,
                            int* __restrict__ hist, int g, int n) {
    int lane = threadIdx.x;
    int orig = (lane < g) ? bsum[lane] : 0;
    int v = orig;
#pragma unroll
    for (int off = 1; off < 64; off <<= 1) {
        int t = __shfl_up(v, off, 64);
        if (lane >= off) v += t;
    }
    if (lane < g) bsum[lane] = v - orig;
    if (lane == 63) row_ptr[n] = v;

    int ho = hist[lane];
    int hv = ho;
#pragma unroll
    for (int off = 1; off < 64; off <<= 1) {
        int t = __shfl_up(hv, off, 64);
        if (lane >= off) hv += t;
    }
    hist[lane] = hv - ho;
}

__global__ void k_build(const int* __restrict__ src, const int* __restrict__ dst,
                        const int* __restrict__ row_raw, const int* __restrict__ bsum,
                        const int* __restrict__ rank, const int* __restrict__ counts,
                        int* __restrict__ row_ptr, int* __restrict__ csr_src,
                        int* __restrict__ hist, int* __restrict__ perm,
                        int n, int e) {
    __shared__ int lh[64];
    __shared__ int gbase[64];
    int tid = threadIdx.x;
    int i = blockIdx.x * 256 + tid;
    bool nodework = (blockIdx.x * 256) < n;
    if (nodework) {
        if (tid < 64) lh[tid] = 0;
        __syncthreads();
        int bucket = 0, myrank = -1;
        if (i < n) {
            int d = counts[i];
            bucket = 63 - (d < 63 ? d : 63);   // LPT: high degree -> low bucket
            myrank = atomicAdd(&lh[bucket], 1);
        }
        __syncthreads();
        if (tid < 64 && lh[tid] > 0) gbase[tid] = atomicAdd(&hist[tid], lh[tid]);
        __syncthreads();
        if (i < n) perm[gbase[bucket] + myrank] = i;
    }
    if (i < n) {
        int rp = row_raw[i] + bsum[i >> 10];
        row_ptr[i] = rp;
        csr_src[rp] = i;
    }
    if (i < e) {
        int d = dst[i];
        int pos = row_raw[d] + bsum[d >> 10] + 1 + rank[i];
        csr_src[pos] = src[i];
    }
}

// ---------------- GAT core: 8 lanes/edge, 8 ch/lane ----------------
// Lane map (within 32-lane half): g = L>>3 edge-group, k = L&7 -> ch k*8..k*8+7.
// Group g handles edges beg+g, beg+g+4, ... (same partition as old 4-unroll).
// Score reduce: head = 16 ch = lanes 2h,2h+1 -> single shfl_xor(1). Reduce
// partner shares the edge predicate (same group) -> divergence-safe.
#define GAT8_STEP(XU)                                                             \
    {                                                                             \
        float xf0 = bflo(XU.x), xf1 = bfhi(XU.x);                                 \
        float xf2 = bflo(XU.y), xf3 = bfhi(XU.y);                                 \
        float xf4 = bflo(XU.z), xf5 = bfhi(XU.z);                                 \
        float xf6 = bflo(XU.w), xf7 = bfhi(XU.w);                                 \
        float u0 = xf0 + xq0; u0 = fmaxf(u0, 0.2f * u0);                          \
        float u1 = xf1 + xq1; u1 = fmaxf(u1, 0.2f * u1);                          \
        float u2 = xf2 + xq2; u2 = fmaxf(u2, 0.2f * u2);                          \
        float u3 = xf3 + xq3; u3 = fmaxf(u3, 0.2f * u3);                          \
        float u4 = xf4 + xq4; u4 = fmaxf(u4, 0.2f * u4);                          \
        float u5 = xf5 + xq5; u5 = fmaxf(u5, 0.2f * u5);                          \
        float u6 = xf6 + xq6; u6 = fmaxf(u6, 0.2f * u6);                          \
        float u7 = xf7 + xq7; u7 = fmaxf(u7, 0.2f * u7);                          \
        float p0_ = (u0 * at0 + u1 * at1) + (u2 * at2 + u3 * at3);                \
        float p1_ = (u4 * at4 + u5 * at5) + (u6 * at6 + u7 * at7);                \
        float p_ = p0_ + p1_;                                                     \
        p_ += __shfl_xor(p_, 1, 64);                                              \
        float pe_ = __expf(fminf(p_, 60.f));                                      \
        lsum += pe_;                                                              \
        A0 += pe_ * xf0; A1 += pe_ * xf1; A2 += pe_ * xf2; A3 += pe_ * xf3;       \
        A4 += pe_ * xf4; A5 += pe_ * xf5; A6 += pe_ * xf6; A7 += pe_ * xf7;       \
    }

// gat phase: node ids from perm; result into sh tile; ids into sid
#define GAT_PHASE_BODY                                                            \
    int tid = threadIdx.x;                                                        \
    int wave = tid >> 6, lane = tid & 63;                                         \
    int half = lane >> 5;                                                         \
    int L = lane & 31;                                                            \
    int g = L >> 3;                                                               \
    int k = L & 7;                                                                \
    int nl = wave * 2 + half;                                                     \
    int idx = blockIdx.x * 16 + nl;                                               \
    bool valid = idx < n;                                                         \
    int v = valid ? perm[idx] : 0;                                                \
    if (L == 0) sid[nl] = valid ? v : -1;                                         \
    uint4 xruv = ((const uint4*)(xr + (size_t)v * 64))[k];                        \
    float xq0 = bflo(xruv.x), xq1 = bfhi(xruv.x);                                 \
    float xq2 = bflo(xruv.y), xq3 = bfhi(xruv.y);                                 \
    float xq4 = bflo(xruv.z), xq5 = bfhi(xruv.z);                                 \
    float xq6 = bflo(xruv.w), xq7 = bfhi(xruv.w);                                 \
    float4 atv0 = ((const float4*)att)[k * 2];                                    \
    float4 atv1 = ((const float4*)att)[k * 2 + 1];                                \
    float at0 = atv0.x, at1 = atv0.y, at2 = atv0.z, at3 = atv0.w;                 \
    float at4 = atv1.x, at5 = atv1.y, at6 = atv1.z, at7 = atv1.w;                 \
    int beg = row_ptr[v];                                                         \
    int end = valid ? row_ptr[v + 1] : beg;                                       \
    float lsum = 0.f;                                                             \
    float A0 = 0.f, A1 = 0.f, A2 = 0.f, A3 = 0.f;                                 \
    float A4 = 0.f, A5 = 0.f, A6 = 0.f, A7 = 0.f;                                 \
    int e = beg + g;                                                              \
    for (; e + 4 < end; e += 8) {                                                 \
        int s0_ = csr_src[e];                                                     \
        int s1_ = csr_src[e + 4];                                                 \
        uint4 xu0_ = ((const uint4*)(xl + (size_t)s0_ * 64))[k];                  \
        uint4 xu1_ = ((const uint4*)(xl + (size_t)s1_ * 64))[k];                  \
        GAT8_STEP(xu0_)                                                           \
        GAT8_STEP(xu1_)                                                           \
    }                                                                             \
    if (e < end) {                                                                \
        int s0_ = csr_src[e];                                                     \
        uint4 xu0_ = ((const uint4*)(xl + (size_t)s0_ * 64))[k];                  \
        GAT8_STEP(xu0_)                                                           \
    }                                                                             \
    lsum += __shfl_xor(lsum, 8, 64);  lsum += __shfl_xor(lsum, 16, 64);           \
    A0 += __shfl_xor(A0, 8, 64);  A0 += __shfl_xor(A0, 16, 64);                   \
    A1 += __shfl_xor(A1, 8, 64);  A1 += __shfl_xor(A1, 16, 64);                   \
    A2 += __shfl_xor(A2, 8, 64);  A2 += __shfl_xor(A2, 16, 64);                   \
    A3 += __shfl_xor(A3, 8, 64);  A3 += __shfl_xor(A3, 16, 64);                   \
    A4 += __shfl_xor(A4, 8, 64);  A4 += __shfl_xor(A4, 16, 64);                   \
    A5 += __shfl_xor(A5, 8, 64);  A5 += __shfl_xor(A5, 16, 64);                   \
    A6 += __shfl_xor(A6, 8, 64);  A6 += __shfl_xor(A6, 16, 64);                   \
    A7 += __shfl_xor(A7, 8, 64);  A7 += __shfl_xor(A7, 16, 64);                   \
    float inv = 1.f / (lsum + 1e-16f);                                            \
    uint4 ruv = ((const uint4*)(res + (size_t)v * 64))[k];                        \
    uint4 huv = ((const uint4*)(h0b + (size_t)v * 64))[k];                        \
    float a = alpha_p[0];                                                         \
    float ac = 1.f - a;                                                           \
    float t0 = a * (A0 * inv + bflo(ruv.x)) + ac * bflo(huv.x);                   \
    float t1 = a * (A1 * inv + bfhi(ruv.x)) + ac * bfhi(huv.x);                   \
    float t2 = a * (A2 * inv + bflo(ruv.y)) + ac * bflo(huv.y);                   \
    float t3 = a * (A3 * inv + bfhi(ruv.y)) + ac * bfhi(huv.y);                   \
    float t4 = a * (A4 * inv + bflo(ruv.z)) + ac * bflo(huv.z);                   \
    float t5 = a * (A5 * inv + bfhi(ruv.z)) + ac * bfhi(huv.z);                   \
    float t6 = a * (A6 * inv + bflo(ruv.w)) + ac * bflo(huv.w);                   \
    float t7 = a * (A7 * inv + bfhi(ruv.w)) + ac * bfhi(huv.w);                   \
    float mu = ((t0 + t1) + (t2 + t3)) + ((t4 + t5) + (t6 + t7));                 \
    mu += __shfl_xor(mu, 1, 64);                                                  \
    mu += __shfl_xor(mu, 2, 64);                                                  \
    mu += __shfl_xor(mu, 4, 64);                                                  \
    mu *= (1.f / 64.f);                                                           \
    float d0 = t0 - mu, d1 = t1 - mu, d2 = t2 - mu, d3 = t3 - mu;                 \
    float d4 = t4 - mu, d5 = t5 - mu, d6 = t6 - mu, d7 = t7 - mu;                 \
    float var = ((d0 * d0 + d1 * d1) + (d2 * d2 + d3 * d3)) +                     \
                ((d4 * d4 + d5 * d5) + (d6 * d6 + d7 * d7));                      \
    var += __shfl_xor(var, 1, 64);                                                \
    var += __shfl_xor(var, 2, 64);                                                \
    var += __shfl_xor(var, 4, 64);                                                \
    var *= (1.f / 64.f);                                                          \
    float rs = rsqrtf(var + 1e-5f);                                               \
    float4 gm0 = ((const float4*)gamma)[k * 2];                                   \
    float4 gm1 = ((const float4*)gamma)[k * 2 + 1];                               \
    float4 bb0_ = ((const float4*)beta)[k * 2];                                   \
    float4 bb1_ = ((const float4*)beta)[k * 2 + 1];                               \
    short8 hs;                                                                    \
    hs[0] = f2bs(gm0.x * d0 * rs + bb0_.x);                                       \
    hs[1] = f2bs(gm0.y * d1 * rs + bb0_.y);                                       \
    hs[2] = f2bs(gm0.z * d2 * rs + bb0_.z);                                       \
    hs[3] = f2bs(gm0.w * d3 * rs + bb0_.w);                                       \
    hs[4] = f2bs(gm1.x * d4 * rs + bb1_.x);                                       \
    hs[5] = f2bs(gm1.y * d5 * rs + bb1_.y);                                       \
    hs[6] = f2bs(gm1.z * d6 * rs + bb1_.z);                                       \
    hs[7] = f2bs(gm1.w * d7 * rs + bb1_.w);                                       \
    if (g == 0) *(short8*)(&sh[nl * 72 + k * 8]) = hs;                            \
    __syncthreads();

// ---------------- gat + next-layer xform fused (16 perm-nodes/block, 512 threads) ----------------
__global__ __launch_bounds__(512) void k_gatx(
        const bf16* __restrict__ xl, const bf16* __restrict__ xr,
        const bf16* __restrict__ res, const bf16* __restrict__ h0b,
        const float* __restrict__ att, const float* __restrict__ gamma,
        const float* __restrict__ beta, const float* __restrict__ alpha_p,
        const int* __restrict__ row_ptr, const int* __restrict__ csr_src,
        const int* __restrict__ perm,
        const bf16* __restrict__ WTn, const float* __restrict__ bln,
        const float* __restrict__ brn, const float* __restrict__ bcn,
        bf16* __restrict__ xlo, bf16* __restrict__ xro, bf16* __restrict__ reso,
        int n) {
    __shared__ __align__(16) short sh[16 * 72];
    __shared__ int sid[16];
    GAT_PHASE_BODY

    int m = lane & 15, q = lane >> 4;
    short8 ha0 = *(const short8*)(&sh[m * 72 + q * 8]);
    short8 ha1 = *(const short8*)(&sh[m * 72 + 32 + q * 8]);
    for (int t = wave; t < 12; t += 8) {
        const short* wp = (const short*)(WTn + (size_t)(t * 16 + m) * 64) + q * 8;
        short8 b0 = *(const short8*)(wp);
        short8 b1 = *(const short8*)(wp + 32);
        f32x4 acc = {0.f, 0.f, 0.f, 0.f};
        acc = __builtin_amdgcn_mfma_f32_16x16x32_bf16(ha0, b0, acc, 0, 0, 0);
        acc = __builtin_amdgcn_mfma_f32_16x16x32_bf16(ha1, b1, acc, 0, 0, 0);
        int col = t * 16 + m;
        int mat = col >> 6, c = col & 63;
        float bias = (mat == 0) ? bln[c] : (mat == 1) ? brn[c] : bcn[c];
        bf16* dst = (mat == 0) ? xlo : (mat == 1) ? xro : reso;
#pragma unroll
        for (int r = 0; r < 4; ++r) {
            int nd = sid[q * 4 + r];
            if (nd >= 0) dst[(size_t)nd * 64 + c] = f2b(acc[r] + bias);
        }
    }
}

// ---------------- last gat + output head fused ----------------
__global__ __launch_bounds__(512) void k_gath(
        const bf16* __restrict__ xl, const bf16* __restrict__ xr,
        const bf16* __restrict__ res, const bf16* __restrict__ h0b,
        const float* __restrict__ att, const float* __restrict__ gamma,
        const float* __restrict__ beta, const float* __restrict__ alpha_p,
        const int* __restrict__ row_ptr, const int* __restrict__ csr_src,
        const int* __restrict__ perm,
        const bf16* __restrict__ W1T, const float* __restrict__ b1,
        const float* __restrict__ W2, const float* __restrict__ b2,
        float* __restrict__ out, int n) {
    __shared__ __align__(16) short sh[16 * 72];
    __shared__ int sid[16];
    GAT_PHASE_BODY

    if (wave == 0) {
        int m = lane & 15, q = lane >> 4;
        short8 ha0 = *(const short8*)(&sh[m * 72 + q * 8]);
        short8 ha1 = *(const short8*)(&sh[m * 72 + 32 + q * 8]);

        const short* w0p = (const short*)(W1T + (size_t)m * 64) + q * 8;
        const short* w1p = (const short*)(W1T + (size_t)(16 + m) * 64) + q * 8;
        short8 b00 = *(const short8*)(w0p);
        short8 b01 = *(const short8*)(w0p + 32);
        short8 b10 = *(const short8*)(w1p);
        short8 b11 = *(const short8*)(w1p + 32);

        f32x4 acc0 = {0.f, 0.f, 0.f, 0.f};
        f32x4 acc1 = {0.f, 0.f, 0.f, 0.f};
        acc0 = __builtin_amdgcn_mfma_f32_16x16x32_bf16(ha0, b00, acc0, 0, 0, 0);
        acc0 = __builtin_amdgcn_mfma_f32_16x16x32_bf16(ha1, b01, acc0, 0, 0, 0);
        acc1 = __builtin_amdgcn_mfma_f32_16x16x32_bf16(ha0, b10, acc1, 0, 0, 0);
        acc1 = __builtin_amdgcn_mfma_f32_16x16x32_bf16(ha1, b11, acc1, 0, 0, 0);

        float w2a = W2[m], w2b = W2[16 + m];
        float bb0 = b1[m], bb1 = b1[16 + m];
        float part[4];
#pragma unroll
        for (int r = 0; r < 4; ++r)
            part[r] = fmaxf(acc0[r] + bb0, 0.f) * w2a + fmaxf(acc1[r] + bb1, 0.f) * w2b;
#pragma unroll
        for (int mask = 1; mask < 16; mask <<= 1) {
#pragma unroll
            for (int r = 0; r < 4; ++r) part[r] += __shfl_xor(part[r], mask, 64);
        }
        if (m == 0) {
            float bb2 = b2[0];
#pragma unroll
            for (int r = 0; r < 4; ++r) {
                int nd = sid[q * 4 + r];
                if (nd >= 0) out[nd] = 1.f / (1.f + __expf(-(part[r] + bb2)));
            }
        }
    }
}

extern "C" void kernel_launch(void* const* d_in, const int* in_sizes, int n_in,
                              void* d_out, int out_size, void* d_ws, size_t ws_size,
                              hipStream_t stream) {
    const float* x     = (const float*)d_in[0];
    const int*   ntype = (const int*)d_in[1];
    const int*   esrc  = (const int*)d_in[2];
    const int*   edst  = (const int*)d_in[3];
    const float* Wt    = (const float*)d_in[4];
    const float* bt    = (const float*)d_in[5];
    const float* Et    = (const float*)d_in[6];
    const float* Wp    = (const float*)d_in[7];
    const float* bp    = (const float*)d_in[8];
    const float* Wl    = (const float*)d_in[9];
    const float* bl    = (const float*)d_in[10];
    const float* Wr    = (const float*)d_in[11];
    const float* br    = (const float*)d_in[12];
    const float* att   = (const float*)d_in[13];
    const float* Wres  = (const float*)d_in[14];
    const float* bconv = (const float*)d_in[15];
    const float* gamma = (const float*)d_in[16];
    const float* beta  = (const float*)d_in[17];
    const float* alpha = (const float*)d_in[18];
    const float* W1    = (const float*)d_in[19];
    const float* b1    = (const float*)d_in[20];
    const float* W2    = (const float*)d_in[21];
    const float* b2    = (const float*)d_in[22];
    float* out = (float*)d_out;

    const int N = in_sizes[1];   // 50000
    const int E = in_sizes[2];   // 800000

    const int G = (N + 1023) / 1024;

    size_t need = 256
                + (size_t)N * 64 * 2 * 7
                + (size_t)36864 * 2 + (size_t)4096 * 2 + (size_t)2048 * 2
                + (size_t)192 * 4
                + (size_t)N * 4
                + (size_t)(N + 1) * 4
                + (size_t)(N + 64) * 4
                + (size_t)N * 4
                + (size_t)E * 4
                + 256
                + (size_t)(E + N) * 4;

    if (ws_size < need) {
        k_sentinel<<<(N + 255) / 256, 256, 0, stream>>>(out, N,
                                                        100.0f + (float)(ws_size >> 20));
        return;
    }

    char* ws = (char*)d_ws;
    ws += 256;
    bf16* h0b   = (bf16*)ws;  ws += (size_t)N * 64 * 2;
    bf16* xlA   = (bf16*)ws;  ws += (size_t)N * 64 * 2;
    bf16* xrA   = (bf16*)ws;  ws += (size_t)N * 64 * 2;
    bf16* resA  = (bf16*)ws;  ws += (size_t)N * 64 * 2;
    bf16* xlB   = (bf16*)ws;  ws += (size_t)N * 64 * 2;
    bf16* xrB   = (bf16*)ws;  ws += (size_t)N * 64 * 2;
    bf16* resB  = (bf16*)ws;  ws += (size_t)N * 64 * 2;
    bf16* WT    = (bf16*)ws;  ws += (size_t)36864 * 2;
    bf16* WpT   = (bf16*)ws;  ws += (size_t)4096 * 2;
    bf16* W1T   = (bf16*)ws;  ws += (size_t)2048 * 2;
    float* TyB  = (float*)ws; ws += (size_t)192 * 4;
    int* row_raw = (int*)ws;  ws += (size_t)N * 4;
    int* row_ptr = (int*)ws;  ws += (size_t)(N + 1) * 4;
    int* counts  = (int*)ws;  ws += (size_t)N * 4;
    int* hist    = (int*)ws;  ws += (size_t)64 * 4;
    int* perm    = (int*)ws;  ws += (size_t)N * 4;
    int* rank    = (int*)ws;  ws += (size_t)E * 4;
    int* bsum    = (int*)ws;  ws += 256;
    int* csr_src = (int*)ws;  ws += (size_t)(E + N) * 4;

    hipMemsetAsync(counts, 0, (size_t)(N + 64) * 4, stream);
    k_setup<<<PREP_BLOCKS + (E + 255) / 256, 256, 0, stream>>>(
        Wl, Wr, Wres, Wp, W1, Et, bp, WT, WpT, W1T, TyB, edst, counts, rank, E);
    k_encx<<<(N + 63) / 64, 256, 0, stream>>>(x, ntype, Wt, bt, WpT, TyB, h0b,
                                              WT, bl, br, bconv, xlA, xrA, resA, N);
    k_scan_local<<<G, 256, 0, stream>>>(counts, row_raw, bsum, hist, N);
    k_scan_bsum<<<1, 64, 0, stream>>>(bsum, row_ptr, hist, G, N);
    k_build<<<(E + 255) / 256, 256, 0, stream>>>(esrc, edst, row_raw, bsum, rank,
                                                 counts, row_ptr, csr_src, hist, perm,
                                                 N, E);

    k_gatx<<<(N + 15) / 16, 512, 0, stream>>>(
        xlA, xrA, resA, h0b, att, gamma, beta, alpha, row_ptr, csr_src, perm,
        WT + 12288, bl + 64, br + 64, bconv + 64, xlB, xrB, resB, N);
    k_gatx<<<(N + 15) / 16, 512, 0, stream>>>(
        xlB, xrB, resB, h0b, att + 64, gamma + 64, beta + 64, alpha, row_ptr, csr_src,
        perm, WT + 24576, bl + 128, br + 128, bconv + 128, xlA, xrA, resA, N);
    k_gath<<<(N + 15) / 16, 512, 0, stream>>>(
        xlA, xrA, resA, h0b, att + 128, gamma + 128, beta + 128, alpha,
        row_ptr, csr_src, perm, W1T, b1, W2, b2, out, N);
}